// Round 1
// baseline (256.006 us; speedup 1.0000x reference)
//
#include <hip/hip_runtime.h>
#include <hip/hip_fp16.h>

// Problem constants (fixed by the reference)
constexpr int L_SITES = 64;    // MPS sites
constexpr int P_DIM   = 4;     // physical dim
constexpr int D_DIM   = 128;   // bond dim
constexpr int B_TOT   = 2048;  // batch
constexpr int G_WG    = 4;     // batch elements per workgroup (1 wave each)
constexpr int NM4     = L_SITES * P_DIM * D_DIM * D_DIM / 4;  // float4 count

// ---------------------------------------------------------------------------
// Pass 1: fp32 -> fp16 conversion of site tensors into workspace.
// fp16 (not bf16): entries ~N(0, D^-0.5) so range is tiny; fp16's 11-bit
// mantissa keeps total chain error ~0.1 absmax vs threshold 1.49.
// ---------------------------------------------------------------------------
__global__ void convert_f16_kernel(const float* __restrict__ src,
                                   __half2* __restrict__ dst) {
  int i = blockIdx.x * blockDim.x + threadIdx.x;
  if (i < NM4) {
    float4 f = ((const float4*)src)[i];
    dst[2 * i]     = __floats2half2_rn(f.x, f.y);
    dst[2 * i + 1] = __floats2half2_rn(f.z, f.w);
  }
}

// ---------------------------------------------------------------------------
// Pass 2: chain kernel. One wave (64 lanes) per batch element, G_WG=4
// elements per 256-thread WG. Lane l owns columns (2l, 2l+1): one dword
// global load per d yields two fp16 matrix entries -> 256B/wave coalesced.
// v double-buffered in LDS, one barrier per site. Occupation string is
// preloaded one-per-lane and broadcast with __shfl (L==64 lanes, exactly).
// ---------------------------------------------------------------------------
__global__ __launch_bounds__(64 * G_WG, 2) void mps_chain_kernel(
    const int* __restrict__ onstate,        // [B, L] int32
    const __half* __restrict__ mats,        // [L, P, D, D] fp16
    const float* __restrict__ left_vec,     // [D]
    const float* __restrict__ right_vec,    // [D]
    float* __restrict__ out)                // [B]
{
  __shared__ float vbuf[2][G_WG][D_DIM];

  const int tid  = threadIdx.x;
  const int g    = tid >> 6;        // element slot in WG (wave index)
  const int lane = tid & 63;
  const int b    = blockIdx.x * G_WG + g;

  // lane l caches onstate[b][l]; broadcast per site via shfl (no loop loads)
  const int s_lane = onstate[b * L_SITES + lane];

  // init v = left_vec
  ((float2*)vbuf[0][g])[lane] = ((const float2*)left_vec)[lane];
  __syncthreads();

  int cur = 0;
  for (int i = 0; i < L_SITES; ++i) {
    const int p = __shfl(s_lane, i, 64);             // wave-uniform occupation
    const __half2* Mx =
        (const __half2*)(mats + ((size_t)(i * P_DIM + p) << 14));  // D*D=16384
    const float4* v4 = (const float4*)vbuf[cur][g];

    float acc0 = 0.f, acc1 = 0.f;
#pragma unroll 8
    for (int dd = 0; dd < D_DIM / 4; ++dd) {
      float4 vv = v4[dd];                            // LDS broadcast, b128
      // M[d][2l..2l+1] as one dword; d = 4dd..4dd+3 (imm-offset friendly)
      float2 m0 = __half22float2(Mx[(4 * dd + 0) * 64 + lane]);
      float2 m1 = __half22float2(Mx[(4 * dd + 1) * 64 + lane]);
      float2 m2 = __half22float2(Mx[(4 * dd + 2) * 64 + lane]);
      float2 m3 = __half22float2(Mx[(4 * dd + 3) * 64 + lane]);
      acc0 = fmaf(vv.x, m0.x, acc0); acc1 = fmaf(vv.x, m0.y, acc1);
      acc0 = fmaf(vv.y, m1.x, acc0); acc1 = fmaf(vv.y, m1.y, acc1);
      acc0 = fmaf(vv.z, m2.x, acc0); acc1 = fmaf(vv.z, m2.y, acc1);
      acc0 = fmaf(vv.w, m3.x, acc0); acc1 = fmaf(vv.w, m3.y, acc1);
    }

    // write v_new to the other buffer; single barrier covers both hazards
    ((float2*)vbuf[cur ^ 1][g])[lane] = make_float2(acc0, acc1);
    __syncthreads();
    cur ^= 1;
  }

  // epilogue: amp = v . right_vec, wave-wide reduction
  float2 rr = ((const float2*)right_vec)[lane];
  float2 vv = ((float2*)vbuf[cur][g])[lane];
  float part = vv.x * rr.x + vv.y * rr.y;
#pragma unroll
  for (int off = 32; off; off >>= 1) part += __shfl_down(part, off, 64);
  if (lane == 0) out[b] = part;
}

// ---------------------------------------------------------------------------
extern "C" void kernel_launch(void* const* d_in, const int* in_sizes, int n_in,
                              void* d_out, int out_size, void* d_ws,
                              size_t ws_size, hipStream_t stream) {
  const int*   onstate      = (const int*)d_in[0];
  const float* site_tensors = (const float*)d_in[1];
  const float* left_vec     = (const float*)d_in[2];
  const float* right_vec    = (const float*)d_in[3];
  float*       out          = (float*)d_out;
  __half*      mats16       = (__half*)d_ws;  // 8.4 MB scratch

  convert_f16_kernel<<<NM4 / 256, 256, 0, stream>>>(site_tensors,
                                                    (__half2*)mats16);
  mps_chain_kernel<<<B_TOT / G_WG, 64 * G_WG, 0, stream>>>(
      onstate, mats16, left_vec, right_vec, out);
}

// Round 2
// 188.635 us; speedup vs baseline: 1.3572x; 1.3572x over previous
//
#include <hip/hip_runtime.h>
#include <hip/hip_fp16.h>

// Problem constants (fixed by the reference)
constexpr int L = 64;     // sites
constexpr int P = 4;      // physical dim
constexpr int D = 128;    // bond dim
constexpr int B = 2048;   // batch
constexpr int EPW = 16;   // batch elements per WG (one mfma M-tile)
constexpr int NWG = B / EPW;  // 128 WGs

using v8h = __attribute__((ext_vector_type(8))) _Float16;  // mfma A/B frag
using v4f = __attribute__((ext_vector_type(4))) float;     // mfma C/D frag

// ---- chain-kernel LDS map (bytes) --------------------------------------
// mbuf[2]: double-buffered chunk = [p=4][c=128][k=64] fp16 = 64 KB each
// vlds[2]: v as fp16 [e=16][d=128] (16B-unit XOR swizzle), 4 KB each
// plds   : onstate staged [site][e] int32, 4 KB
constexpr int MBUF0 = 0;
constexpr int MBUF1 = 65536;
constexpr int VLDS0 = 131072;
constexpr int VLDS1 = 131072 + 4096;
constexpr int PLDS  = 131072 + 8192;
constexpr int SMEM_BYTES = PLDS + L * EPW * 4;  // 143360 (<=160KB/CU, 1 WG/CU)

// async global->LDS, 16B per lane (LDS dest = uniform base + lane*16,
// global src per-lane -> lets us bake the inverse XOR swizzle into src addr)
__device__ __forceinline__ void gl2lds16(const void* g, void* l) {
  __builtin_amdgcn_global_load_lds(
      (const __attribute__((address_space(1))) void*)g,
      (__attribute__((address_space(3))) void*)l, 16, 0, 0);
}

// ---------------------------------------------------------------------------
// Convert + transpose: fp32 [site][p][d][c] -> fp16 [site][p][c][d]
// (column-major per matrix so B-fragments & staging are contiguous along d).
// 64x64 tiles through LDS; coalesced reads, 16B writes in 64B runs.
// ---------------------------------------------------------------------------
__global__ void convert_transpose_kernel(const float* __restrict__ src,
                                         _Float16* __restrict__ dst) {
  __shared__ _Float16 lt[64 * 72];  // 64x64 tile, pad 72 to break banks
  const int bx = blockIdx.x;
  const int mat = bx >> 2;          // site*P + p
  const int ti = (bx >> 1) & 1;     // d-block
  const int tj = bx & 1;            // c-block
  const float* sb = src + (size_t)mat * (D * D) + ti * 64 * D + tj * 64;
  const int t = threadIdx.x;
#pragma unroll
  for (int it = 0; it < 4; ++it) {
    int idx = t + it * 256;
    int r = idx >> 4, f4 = idx & 15;          // row in tile, float4 col
    float4 f = *(const float4*)(sb + r * D + f4 * 4);
    _Float16* q = &lt[r * 72 + f4 * 4];
    q[0] = (_Float16)f.x; q[1] = (_Float16)f.y;
    q[2] = (_Float16)f.z; q[3] = (_Float16)f.w;
  }
  __syncthreads();
  _Float16* db = dst + (size_t)mat * (D * D);
#pragma unroll
  for (int it = 0; it < 2; ++it) {
    int idx = t + it * 256;
    int cl = idx >> 3, seg = idx & 7;         // tile col, 8-half d-segment
    v8h v;
#pragma unroll
    for (int j = 0; j < 8; ++j) v[j] = lt[(seg * 8 + j) * 72 + cl];
    *(v8h*)(db + (tj * 64 + cl) * D + ti * 64 + seg * 8) = v;
  }
}

// ---------------------------------------------------------------------------
// Chain kernel: 128 WGs x 4 waves x 16 elements.
// Per site: V_new[16 x 128] = sum_p (V masked to s==p) @ A[site][p],
// via mfma_f32_16x16x32_f16; all 4 matrices staged in LDS (shared by the
// 16 elements -> 4x less L2 traffic), 64-KB d-chunks double-buffered with
// global_load_lds (m97-style 2-barrier pipeline).
// Frag layouts (m89/m92-verified): A[m=lane&15][k=(lane>>4)*8+j],
// B^T[n=lane&15][k=(lane>>4)*8+j], C[row=(lane>>4)*4+r][col=lane&15].
// 16B-unit XOR swizzle (slot ^= c&7 / e&7) breaks 128B-stride bank folding;
// staging applies the inverse swizzle on the per-lane global address.
// ---------------------------------------------------------------------------
__global__ __launch_bounds__(256, 1) void mps_mfma_chain(
    const int* __restrict__ onstate, const _Float16* __restrict__ mt,
    const float* __restrict__ left_vec, const float* __restrict__ right_vec,
    float* __restrict__ out) {
  extern __shared__ char smem[];
  const int tid = threadIdx.x;
  const int wave = tid >> 6, lane = tid & 63;
  const int me = lane & 15, q4 = lane >> 4;
  const int b0 = blockIdx.x * EPW;

  // ---- stage onstate -> plds[site][e]
  int* plds = (int*)(smem + PLDS);
  {
    int e = tid >> 6, i = tid & 63;
#pragma unroll
    for (int j = 0; j < 4; ++j)
      plds[i * EPW + (e + j * 4)] = onstate[(b0 + e + j * 4) * L + i];
  }
  // ---- init vlds0: v = left_vec for every element (swizzled write)
  {
    int e = tid >> 4, dseg = tid & 15;
    _Float16* vp = (_Float16*)(smem + VLDS0) + e * 128 + (dseg ^ (e & 7)) * 8;
#pragma unroll
    for (int j = 0; j < 8; ++j) vp[j] = (_Float16)left_vec[dseg * 8 + j];
  }
  // ---- per-lane staging source offset (inverse swizzle baked in)
  const int lrow = lane >> 3;                   // c within 8-row group
  const int lslot = (lane & 7) ^ lrow;          // global d-segment for my slot
  const int laneoff = lrow * 256 + lslot * 16;  // bytes into [c][d] matrix

  // ---- prologue: stage chunk 0 (site 0, lower d-half); wave stages p=wave
  {
    const char* gsrc = (const char*)mt + wave * 32768 + laneoff;
    char* ldst = smem + MBUF0 + wave * 16384;
#pragma unroll
    for (int i = 0; i < 16; ++i)
      gl2lds16(gsrc + i * 2048, ldst + i * 1024);
  }
  __syncthreads();

  int cur = 0;
  for (int site = 0; site < L; ++site) {
    const int pm = plds[site * EPW + me];  // my M-row's occupation this site
    v4f acc0 = {0.f, 0.f, 0.f, 0.f}, acc1 = {0.f, 0.f, 0.f, 0.f};
#pragma unroll
    for (int h = 0; h < 2; ++h) {          // two 64-d chunks per site
      const int g = site * 2 + h;
      // -- stage next chunk into the other buffer (overlaps this compute)
      if (g < 2 * L - 1) {
        const int gn = g + 1, s2 = gn >> 1, h2 = gn & 1;
        const char* gsrc =
            (const char*)mt + (s2 * 4 + wave) * 32768 + h2 * 128 + laneoff;
        char* ldst = smem + ((gn & 1) ? MBUF1 : MBUF0) + wave * 16384;
#pragma unroll
        for (int i = 0; i < 16; ++i)
          gl2lds16(gsrc + i * 2048, ldst + i * 1024);
      }
      // -- A fragments (kc=0,1) from vlds[cur], swizzled b128
      const char* vb = smem + (cur ? VLDS1 : VLDS0);
      const int s0 = h * 8 + q4, s1 = h * 8 + 4 + q4;
      v8h a0 = *(const v8h*)(vb + me * 256 + (s0 ^ (me & 7)) * 16);
      v8h a1 = *(const v8h*)(vb + me * 256 + (s1 ^ (me & 7)) * 16);

      const char* mb = smem + ((g & 1) ? MBUF1 : MBUF0);
      const int c0 = wave * 32 + me;       // my two output-column tiles
      const int c1 = wave * 32 + 16 + me;
#pragma unroll
      for (int p = 0; p < P; ++p) {
        const bool isp = (pm == p);
        v8h z = {};
        v8h am0 = isp ? a0 : z;
        v8h am1 = isp ? a1 : z;
        const char* pb = mb + p * 16384;
        v8h b00 = *(const v8h*)(pb + c0 * 128 + ((q4 ^ (c0 & 7)) * 16));
        v8h b01 = *(const v8h*)(pb + c0 * 128 + (((4 + q4) ^ (c0 & 7)) * 16));
        acc0 = __builtin_amdgcn_mfma_f32_16x16x32_f16(am0, b00, acc0, 0, 0, 0);
        acc0 = __builtin_amdgcn_mfma_f32_16x16x32_f16(am1, b01, acc0, 0, 0, 0);
        v8h b10 = *(const v8h*)(pb + c1 * 128 + ((q4 ^ (c1 & 7)) * 16));
        v8h b11 = *(const v8h*)(pb + c1 * 128 + (((4 + q4) ^ (c1 & 7)) * 16));
        acc1 = __builtin_amdgcn_mfma_f32_16x16x32_f16(am0, b10, acc1, 0, 0, 0);
        acc1 = __builtin_amdgcn_mfma_f32_16x16x32_f16(am1, b11, acc1, 0, 0, 0);
      }
      if (h == 1) {
        // -- write v_new (fp16) to the other v-buffer, swizzled
        _Float16* vn = (_Float16*)(smem + (cur ? VLDS0 : VLDS1));
#pragma unroll
        for (int r = 0; r < 4; ++r) {
          int e = q4 * 4 + r, sw = e & 7;
          vn[e * 128 + ((c0 >> 3) ^ sw) * 8 + (c0 & 7)] = (_Float16)acc0[r];
          vn[e * 128 + ((c1 >> 3) ^ sw) * 8 + (c1 & 7)] = (_Float16)acc1[r];
        }
      }
      __syncthreads();  // drains global_load_lds (vmcnt) + LDS hazards
    }
    cur ^= 1;
  }

  // ---- epilogue: out[b] = v . right_vec (wave 0 only; 4 lanes per element)
  if (wave == 0) {
    const char* vb = smem + (cur ? VLDS1 : VLDS0);
    const int e = lane >> 2, dg = lane & 3;
    float part = 0.f;
#pragma unroll
    for (int u = 0; u < 4; ++u) {
      int s = dg * 4 + u;
      v8h v = *(const v8h*)(vb + e * 256 + ((s ^ (e & 7)) * 16));
#pragma unroll
      for (int j = 0; j < 8; ++j) part += (float)v[j] * right_vec[s * 8 + j];
    }
    part += __shfl_xor(part, 1, 64);
    part += __shfl_xor(part, 2, 64);
    if ((lane & 3) == 0) out[b0 + e] = part;
  }
}

// ---------------------------------------------------------------------------
extern "C" void kernel_launch(void* const* d_in, const int* in_sizes, int n_in,
                              void* d_out, int out_size, void* d_ws,
                              size_t ws_size, hipStream_t stream) {
  const int*   onstate      = (const int*)d_in[0];
  const float* site_tensors = (const float*)d_in[1];
  const float* left_vec     = (const float*)d_in[2];
  const float* right_vec    = (const float*)d_in[3];
  float*       out          = (float*)d_out;
  _Float16*    mt           = (_Float16*)d_ws;  // 8.4 MB transposed fp16

  // allow >64KB dynamic LDS (143,360 B); host-side attr set, capture-safe
  hipFuncSetAttribute((const void*)mps_mfma_chain,
                      hipFuncAttributeMaxDynamicSharedMemorySize, SMEM_BYTES);

  convert_transpose_kernel<<<L * P * 4, 256, 0, stream>>>(site_tensors, mt);
  mps_mfma_chain<<<NWG, 256, SMEM_BYTES, stream>>>(onstate, mt, left_vec,
                                                   right_vec, out);
}